// Round 1
// 89.754 us; speedup vs baseline: 1.0513x; 1.0513x over previous
//
#include <hip/hip_runtime.h>

#define EPS 5e-4f
#define LOG2E 1.4426950408889634f
#define BATCH 32
#define N 2048
#define QW 32              // ws partial slices per row
#define TBINS 2048         // float sigma LUT, 8 KB; t = (pa-pb)*log2e in [-16,16)
#define TSCALE 256.0f      // 4 bytes * 64 bins per t-unit
#define TMAGIC 12587008.0f // 1.5*2^23 + 16*256: mantissa low bits = byte offset
#define FSLICE 8           // finalize blocks per row (256 k's each)

__device__ __forceinline__ float fexp2(float x) { return __builtin_amdgcn_exp2f(x); }
__device__ __forceinline__ float frcp(float x)  { return __builtin_amdgcn_rcpf(x); }
// full-wave rotate by 1 lane via DPP (HW-verified R4/R5, absmax 0.0)
__device__ __forceinline__ float rot1f(float x) {
    return __int_as_float(__builtin_amdgcn_update_dpp(
        0, __float_as_int(x), 0x134 /* wave_rol:1 */, 0xF, 0xF, false));
}

// S_k = sum_{l != k} sigmoid(p_l - p_k). Pair coverage identical to R4/R5
// (HW-verified). sigma evaluation is STATICALLY INTERLEAVED between two paths
// to load both pipes (R4/R5 measurements: trans shares the VALU at 8cyc/op;
// LDS gather throughput ~5.8cyc/CU is the pure-LUT binding pipe):
//   LUT  (5/7 of pairs): fma + and + ds_read_b32  -> DS pipe + 12 VALU-cyc
//   trans(2/7 of pairs): sub + v_exp + add + v_rcp -> 28 VALU-cyc, 0 DS
// Float LUT with magic-number indexing (bits of fma result = byte offset):
// no cvt, no shifts, one shared float accumulator for both paths.
//
// R6: task-stripe offset rotated by u. Previously group q=0 always took the
// 33rd tile-task, and q=0 is wave 0 of even-bx blocks -> SIMD0 of every CU
// carried 18 task-units vs 16 on SIMD1..3 (~9% makespan tail). With
// t0 = (q+u)&7 the long group migrates across waves per block; the 4
// resident blocks per CU have different u, so per-SIMD load evens out.
__global__ __launch_bounds__(256) void pairs_kernel(const float* __restrict__ y_pred,
                                                    float* __restrict__ ws,
                                                    float* __restrict__ out) {
    const int r  = blockIdx.y, bx = blockIdx.x;
    const int u  = bx >> 1, h = bx & 1, v = 31 - u;
    const int tid = threadIdx.x, lane = tid & 63, wave = tid >> 6;
    __shared__ float tabf[TBINS];   // 8 KB
    __shared__ float scol[4 * N];   // 32 KB: per-wave private S copies

    if (r == 0 && bx == 0 && tid == 0) out[0] = 0.f;  // replaces memset dispatch

    for (int i = tid; i < TBINS; i += 256) {
        float t_c = (i + 0.5f) * (1.f / 64.f) - 16.f;  // bin-center t
        tabf[i] = 1.f / (1.f + exp2f(t_c));            // sigma(p_b-p_a), t=(pa-pb)log2e
    }
    for (int c = tid; c < 4 * N; c += 256) scol[c] = 0.f;
    __syncthreads();

    const float* yp = y_pred + r * N;   // tile reads straight from L2
    float* myS = &scol[wave * N];

    const int q = h + 2 * wave;         // 0..7; 33 tile-tasks per (u,v) pair
    for (int t = (q + u) & 7; t < 33; t += 8) {
        int i, j;
        if (t == 0)      { i = u; j = u; }
        else if (t == 1) { i = v; j = v; }
        else {
            int o = t - 2;
            int onU = (o < 31 - u);
            i = onU ? u : v;
            j = onU ? (u + 1 + o) : (v + 1 + (o - (31 - u)));
        }
        const float aL2 = yp[i * 64 + lane] * LOG2E;
        float bb = yp[j * 64 + lane] * LOG2E;
        const float aoff = fmaf(aL2, TSCALE, TMAGIC);   // hoisted index base
        float accA = 0.f, accBn = 0.f;

        if (i != j) {
            // off-diagonal 64x64 tile: 64 rotations, both directions per pair
#pragma unroll
            for (int jj = 0; jj < 64; ++jj) {
                if (jj) bb = rot1f(bb);
                float rr;
                if (jj % 7 < 2) {
                    rr = frcp(1.f + fexp2(aL2 - bb));          // exact path
                } else {
                    float z = fmaf(bb, -TSCALE, aoff);         // 4q + magic
                    rr = *(const float*)((const char*)tabf +
                                         (__float_as_uint(z) & 0x1FFC));
                }
                accA  += rr;           // row credit (lane a)
                accBn += rr;           // col credit, rotating accumulator
                accBn = rot1f(accBn);
            }
            myS[i * 64 + lane] += accA;
            myS[j * 64 + lane] += 64.f - accBn;
        } else {
            // diagonal: jj=1..31 both credits, jj=32 row-credit only (R4 logic)
#pragma unroll
            for (int jj = 0; jj < 33; ++jj) {
                if (jj) bb = rot1f(bb);
                if (jj >= 1) {
                    float z = fmaf(bb, -TSCALE, aoff);
                    float rr = *(const float*)((const char*)tabf +
                                               (__float_as_uint(z) & 0x1FFC));
                    accA += rr;
                    if (jj <= 31) accBn += rr;
                }
                accBn = rot1f(accBn);
            }
#pragma unroll
            for (int e = 0; e < 31; ++e) accBn = rot1f(accBn);
            myS[i * 64 + lane] += accA;
            myS[j * 64 + lane] += 31.f - accBn;
        }
    }
    __syncthreads();

    float* wsl = ws + ((size_t)r * QW + bx) * N;
    for (int c = tid; c < N; c += 256)
        wsl[c] = scol[c] + scol[N + c] + scol[2 * N + c] + scol[3 * N + c];
}

// R6: 8 blocks per row (grid 256) instead of 1 -> 8x the CUs active on the
// ws-read sweep. The 5-bin histogram + maxDCG rank-sweep is recomputed
// redundantly per block (y_true row is 8 KB, L2-hot; sweep is 8 iters/thread)
// -- negligible vs the 8x parallelism on the 8 MB ws reduction.
__global__ __launch_bounds__(256) void finalize_kernel(const float* __restrict__ y_true,
                                                       const float* __restrict__ ws,
                                                       float* __restrict__ out) {
    const int r   = blockIdx.y;
    const int s   = blockIdx.x;          // k-slice: [s*256, s*256+256)
    const int tid = threadIdx.x;
    __shared__ int cnt[5];
    __shared__ float red[256];
    if (tid < 5) cnt[tid] = 0;
    __syncthreads();

    const float* yt = y_true + r * N;
    int c1 = 0, c2 = 0, c3 = 0, c4 = 0;
    for (int i = tid; i < N; i += 256) {
        int vv = (int)yt[i];
        c1 += (vv == 1); c2 += (vv == 2); c3 += (vv == 3); c4 += (vv == 4);
    }
    atomicAdd(&cnt[1], c1);
    atomicAdd(&cnt[2], c2);
    atomicAdd(&cnt[3], c3);
    atomicAdd(&cnt[4], c4);
    __syncthreads();

    const int cum4 = cnt[4];
    const int cum3 = cum4 + cnt[3];
    const int cum2 = cum3 + cnt[2];
    const int cum1 = cum2 + cnt[1];

    float part = 0.f;
    for (int rr = tid + 1; rr <= N; rr += 256) {
        float g = (rr <= cum4) ? 15.f : (rr <= cum3) ? 7.f
                : (rr <= cum2) ? 3.f  : (rr <= cum1) ? 1.f : 0.f;
        if (g > 0.f) part += g / __log2f((float)(1 + rr));
    }
    red[tid] = part;
    __syncthreads();
    for (int st = 128; st > 0; st >>= 1) {
        if (tid < st) red[tid] += red[tid + st];
        __syncthreads();
    }
    const float invD = 1.f / fmaxf(red[0], EPS);
    __syncthreads();                     // red[] reused below

    // one k per thread
    const int k = s * 256 + tid;
    float S = 0.f;
    const float* p = ws + (size_t)r * QW * N + k;
#pragma unroll
    for (int q = 0; q < QW; ++q) S += p[q * N];
    float pos = 1.f + S;                 // self term excluded in pairs_kernel
    float aD  = __log2f(1.f + pos);
    float g   = (fexp2(yt[k]) - 1.f) * invD;
    red[tid]  = g / aD;
    __syncthreads();
    for (int st = 128; st > 0; st >>= 1) {
        if (tid < st) red[tid] += red[tid + st];
        __syncthreads();
    }
    if (tid == 0) atomicAdd(out, red[0] * (1.f / BATCH));
}

extern "C" void kernel_launch(void* const* d_in, const int* in_sizes, int n_in,
                              void* d_out, int out_size, void* d_ws, size_t ws_size,
                              hipStream_t stream) {
    const float* y_pred = (const float*)d_in[0];
    const float* y_true = (const float*)d_in[1];
    float* out = (float*)d_out;
    float* ws  = (float*)d_ws;   // 32 rows x 32 slices x 2048 floats = 8 MB

    pairs_kernel<<<dim3(QW, BATCH), dim3(256), 0, stream>>>(y_pred, ws, out);
    finalize_kernel<<<dim3(FSLICE, BATCH), dim3(256), 0, stream>>>(y_true, ws, out);
}